// Round 4
// baseline (258.685 us; speedup 1.0000x reference)
//
#include <hip/hip_runtime.h>

// Fused: h = relu(X @ M + d), s0 = sum(h), where
//   M = W^T @ RW (20x20), d = b @ RW + 1 (20,)  -- precomputed by setup_kernel.
// Then n = #halvings of f32(s0) until <= 1; out = f32(s0) * 2^-n.
//
// Round-9: wave-local LDS transpose (combine R1's coalescing with R3's
// occupancy, drop each one's weakness):
//  * Each wave stages ONLY its own 64 rows (5,120B): 5 fully-coalesced
//    float4 loads (16 lines/instr vs 64 for the direct per-row pattern;
//    4x fewer TA line requests) -> 5 ds_write_b128 -> 5 ds_read_b128 at
//    base 5*lane (odd f4 stride => all 8 bank-quads => conflict-free,
//    zero padding).
//  * NO block barrier anywhere in the body; ordering is wave-local lgkmcnt
//    (compiler-inserted: write/read alias the same LDS array). Waves drift.
//  * NO global_load_lds DMA (R2 proved vmcnt(0) round-trips serialize).
//  * One 256-row chunk per block (7813 blocks): no chunk loop, no LDS WAR.
//    LDS = 20.5KB -> 7 blocks/CU (28 waves/CU) vs R1's 3 blocks (12 waves).
//  * Mt/dvec stay uniform-CF s_load (scalar pipe, sK$) -- verified win.
//  * Merged last-block finalize via ticket -- verified win (~4us). Finalize
//    sum now uses 4 independent accumulators (ILP) since partials grew to
//    7813 slots.

#define D 20
#define BLOCK 256
#define WAVE_ROWS 64
#define WAVE_F4 (WAVE_ROWS * D / 4)    // 320 float4 per wave slice (5,120B)
#define BLOCK_F4 (BLOCK * D / 4)       // 1280 float4 per block (20,480B)
#define WS_PARTIALS_BYTES 65536

// d_ws layout:
//   [0, 65536)            : double partials[8192] (one per block; 7813 used)
//   [65536, +1600)        : float Mt[400], Mt[j*D+k] = M[k][j]
//   [+1600, +1680)        : float dvec[20]
//   [+1680, +1684)        : unsigned counter (last-block ticket)

__global__ void setup_kernel(const float* __restrict__ W,
                             const float* __restrict__ b,
                             const float* __restrict__ RW,
                             float* __restrict__ Mt,
                             float* __restrict__ dvec,
                             unsigned* __restrict__ counter) {
    const int tid = threadIdx.x;
    if (tid == 0) *counter = 0u;  // ws is re-poisoned each iteration
    for (int idx = tid; idx < D * D; idx += blockDim.x) {
        const int j = idx / D, k = idx % D;
        float s = 0.0f;
        for (int i = 0; i < D; ++i)
            s = fmaf(W[i * D + k], RW[i * D + j], s);
        Mt[idx] = s;  // idx == j*D + k
    }
    if (tid < D) {
        float s = 1.0f;
        for (int i = 0; i < D; ++i)
            s = fmaf(b[i], RW[i * D + tid], s);
        dvec[tid] = s;
    }
}

__global__ void __launch_bounds__(BLOCK)
fused_mlp_sum(const float* __restrict__ X,
              const float* __restrict__ Mt,
              const float* __restrict__ dvec,
              double* __restrict__ partials,
              unsigned* __restrict__ counter,
              float* __restrict__ out,
              int nrows) {
    __shared__ float4 lds4[BLOCK_F4];      // 20,480 B, linear, unpadded
    __shared__ float wave_sums[BLOCK / 64];
    __shared__ double dsum[BLOCK / 64];
    __shared__ int is_last;

    const int tid  = threadIdx.x;
    const int lane = tid & 63;
    const int wave = tid >> 6;
    const int bid  = blockIdx.x;

    // Thread's row == its position in the block's 256-row chunk.
    const long long row = (long long)bid * BLOCK + tid;
    const bool valid = row < (long long)nrows;

    // ---- Stage: 5 coalesced float4 loads -> own wave's LDS slice ----
    const long long max_f4 = (long long)nrows * (D / 4) - 1;
    const long long wbase_f4 = (long long)bid * BLOCK_F4 + wave * WAVE_F4;
    const float4* __restrict__ xg4 = (const float4*)X;
    float4* const wl = lds4 + wave * WAVE_F4;  // this wave's private slice

    float4 st[5];
#pragma unroll
    for (int q = 0; q < 5; ++q) {
        long long s = wbase_f4 + 64 * q + lane;   // lane-contiguous 1KB/instr
        s = (s <= max_f4) ? s : max_f4;           // clamp tail (stay in-bounds)
        st[q] = xg4[s];
    }
#pragma unroll
    for (int q = 0; q < 5; ++q)
        wl[64 * q + lane] = st[q];                // ds_write_b128, linear

    // ---- Own row from LDS: base 5*lane (odd) => conflict-free b128 ----
    // Wave-local ordering only: compiler inserts lgkmcnt for the alias.
    float x[D];
#pragma unroll
    for (int q = 0; q < 5; ++q) {
        const float4 v = wl[5 * lane + q];
        x[4 * q + 0] = v.x; x[4 * q + 1] = v.y;
        x[4 * q + 2] = v.z; x[4 * q + 3] = v.w;
    }

    // ---- 20x20 FMA; Mt/dvec uniform-CF -> s_load (scalar pipe) ----
    float lsum = 0.0f;
#pragma unroll
    for (int j = 0; j < D; ++j) {
        float t = dvec[j];
#pragma unroll
        for (int k = 0; k < D; ++k)
            t = fmaf(x[k], Mt[j * D + k], t);   // v_fma with SGPR src
        lsum += fmaxf(t, 0.0f);
    }
    lsum = valid ? lsum : 0.0f;  // mask clamped tail lanes

    // ---- Block reduction -> one partial per block ----
#pragma unroll
    for (int off = 32; off > 0; off >>= 1)
        lsum += __shfl_down(lsum, off, 64);
    if (lane == 0) wave_sums[wave] = lsum;
    __syncthreads();

    if (tid == 0) {
        const float bs = wave_sums[0] + wave_sums[1] + wave_sums[2] + wave_sums[3];
        // Release store + acq_rel ticket: visible to last block cross-XCD.
        __hip_atomic_store(&partials[bid], (double)bs, __ATOMIC_RELEASE,
                           __HIP_MEMORY_SCOPE_AGENT);
        const unsigned tk = __hip_atomic_fetch_add(counter, 1u, __ATOMIC_ACQ_REL,
                                                   __HIP_MEMORY_SCOPE_AGENT);
        is_last = (tk == gridDim.x - 1);
    }
    __syncthreads();

    // ---- Last block finalizes (no separate launch) ----
    if (is_last) {
        const int G = (int)gridDim.x;
        double a0 = 0.0, a1 = 0.0, a2 = 0.0, a3 = 0.0;  // 4-way ILP
        int i = tid;
        for (; i + 3 * BLOCK < G; i += 4 * BLOCK) {
            a0 += __hip_atomic_load(&partials[i], __ATOMIC_RELAXED,
                                    __HIP_MEMORY_SCOPE_AGENT);
            a1 += __hip_atomic_load(&partials[i + BLOCK], __ATOMIC_RELAXED,
                                    __HIP_MEMORY_SCOPE_AGENT);
            a2 += __hip_atomic_load(&partials[i + 2 * BLOCK], __ATOMIC_RELAXED,
                                    __HIP_MEMORY_SCOPE_AGENT);
            a3 += __hip_atomic_load(&partials[i + 3 * BLOCK], __ATOMIC_RELAXED,
                                    __HIP_MEMORY_SCOPE_AGENT);
        }
        for (; i < G; i += BLOCK)
            a0 += __hip_atomic_load(&partials[i], __ATOMIC_RELAXED,
                                    __HIP_MEMORY_SCOPE_AGENT);
        double sd = (a0 + a1) + (a2 + a3);
#pragma unroll
        for (int off = 32; off > 0; off >>= 1)
            sd += __shfl_down(sd, off, 64);
        if (lane == 0) dsum[wave] = sd;
        __syncthreads();
        if (tid == 0) {
            const double s0 = dsum[0] + dsum[1] + dsum[2] + dsum[3];
            float f = (float)s0;   // reference's s0 is f32
            while (f > 1.0f) f *= 0.5f;  // exact power-of-2 halvings
            out[0] = f;
        }
    }
}

extern "C" void kernel_launch(void* const* d_in, const int* in_sizes, int n_in,
                              void* d_out, int out_size, void* d_ws, size_t ws_size,
                              hipStream_t stream) {
    const float* X  = (const float*)d_in[0];
    const float* W  = (const float*)d_in[1];
    const float* b  = (const float*)d_in[2];
    const float* RW = (const float*)d_in[3];
    float* out = (float*)d_out;

    double* partials = (double*)d_ws;
    float*  Mt = (float*)((char*)d_ws + WS_PARTIALS_BYTES);
    float*  dv = Mt + D * D;
    unsigned* counter = (unsigned*)((char*)d_ws + WS_PARTIALS_BYTES + 1600 + 80);

    const int nrows = in_sizes[0] / (D * 4);  // 2,000,000

    setup_kernel<<<1, 256, 0, stream>>>(W, b, RW, Mt, dv, counter);

    const int blocks = (nrows + BLOCK - 1) / BLOCK;  // 7813
    fused_mlp_sum<<<blocks, BLOCK, 0, stream>>>(X, Mt, dv, partials, counter,
                                                out, nrows);
}

// Round 6
// 258.484 us; speedup vs baseline: 1.0008x; 1.0008x over previous
//
#include <hip/hip_runtime.h>

// Fused: h = relu(X @ M + d), s0 = sum(h), where
//   M = W^T @ RW (20x20), d = b @ RW + 1 (20,)  -- precomputed by setup_kernel.
// Then n = #halvings of f32(s0) until <= 1; out = f32(s0) * 2^-n.
//
// Round-11 == Round-10 resubmitted verbatim (round-5 bench died on GPU
// acquisition timeout; no data). Rationale recap:
//  Empirical matrix (R0-R4): LDS staging WITHOUT a block barrier stalls
//  catastrophically (R2 DMA: 110us; R4 wave-local: 110us; all pipes <6%
//  busy) -- the per-wave load->vmcnt->ds_write->ds_read chain does not
//  overlap across waves. WITH a barrier (R1) or with no LDS at all (R3),
//  fused runs ~30us. So: keep the barrier, fix R1's real weakness instead:
//  its 45KB padded LDS capped occupancy at 3 blocks/CU (12 waves).
//   * RPT=1: block chunk = 256 rows = 1280 float4 = 20,480B. Read base
//     becomes 5*tid (ODD float4 stride) => ds_read_b128 cycles all 8
//     bank-quads => conflict-free with ZERO padding (R1's pad existed only
//     because 10*tid was even). LDS 45KB -> 20.5KB => 7 blocks/CU, 28 waves.
//   * Stage: 5 fully-coalesced float4 loads (lane-contiguous 1KB/instr,
//     16 lines/instr vs 64 for direct per-row loads) -> 5 linear
//     ds_write_b128 -> __syncthreads -> 5 conflict-free ds_read_b128.
//   * UNIFORM control flow throughout => Mt/dvec scalarize to s_load
//     (scalar pipe, sK$); tail handled by clamp+mask, not branch.
//   * Merged last-block finalize via ticket (verified ~4us win), 4-way ILP
//     partial sum (7813 partials).

#define D 20
#define BLOCK 256
#define CHUNK_F4 (BLOCK * D / 4)   // 1280 float4 = 20,480 B per block
#define WS_PARTIALS_BYTES 65536

// d_ws layout:
//   [0, 65536)            : double partials[8192] (one per block; 7813 used)
//   [65536, +1600)        : float Mt[400], Mt[j*D+k] = M[k][j]
//   [+1600, +1680)        : float dvec[20]
//   [+1680, +1684)        : unsigned counter (last-block ticket)

__global__ void setup_kernel(const float* __restrict__ W,
                             const float* __restrict__ b,
                             const float* __restrict__ RW,
                             float* __restrict__ Mt,
                             float* __restrict__ dvec,
                             unsigned* __restrict__ counter) {
    const int tid = threadIdx.x;
    if (tid == 0) *counter = 0u;  // ws is re-poisoned each iteration
    for (int idx = tid; idx < D * D; idx += blockDim.x) {
        const int j = idx / D, k = idx % D;
        float s = 0.0f;
        for (int i = 0; i < D; ++i)
            s = fmaf(W[i * D + k], RW[i * D + j], s);
        Mt[idx] = s;  // idx == j*D + k
    }
    if (tid < D) {
        float s = 1.0f;
        for (int i = 0; i < D; ++i)
            s = fmaf(b[i], RW[i * D + tid], s);
        dvec[tid] = s;
    }
}

__global__ void __launch_bounds__(BLOCK)
fused_mlp_sum(const float* __restrict__ X,
              const float* __restrict__ Mt,
              const float* __restrict__ dvec,
              double* __restrict__ partials,
              unsigned* __restrict__ counter,
              float* __restrict__ out,
              int nrows) {
    __shared__ float4 lds4[CHUNK_F4];      // 20,480 B, linear, unpadded
    __shared__ float wave_sums[BLOCK / 64];
    __shared__ double dsum[BLOCK / 64];
    __shared__ int is_last;

    const int tid  = threadIdx.x;
    const int lane = tid & 63;
    const int wave = tid >> 6;
    const int bid  = blockIdx.x;

    const long long row = (long long)bid * BLOCK + tid;  // 1 row / thread
    const bool valid = row < (long long)nrows;

    // ---- Stage: 5 block-wide coalesced float4 loads -> linear LDS ----
    const long long max_f4 = (long long)nrows * (D / 4) - 1;
    const long long base_f4 = (long long)bid * CHUNK_F4;
    const float4* __restrict__ xg4 = (const float4*)X;

    float4 st[5];
#pragma unroll
    for (int q = 0; q < 5; ++q) {
        long long s = base_f4 + BLOCK * q + tid;  // lane-contiguous 1KB/instr
        s = (s <= max_f4) ? s : max_f4;           // clamp tail, stay in-bounds
        st[q] = xg4[s];
    }
#pragma unroll
    for (int q = 0; q < 5; ++q)
        lds4[BLOCK * q + tid] = st[q];            // linear ds_write_b128
    __syncthreads();   // the barrier IS the point: block-dense staging drain

    // ---- Own row: base 5*tid (odd f4 stride) => conflict-free b128 ----
    float x[D];
#pragma unroll
    for (int q = 0; q < 5; ++q) {
        const float4 v = lds4[5 * tid + q];
        x[4 * q + 0] = v.x; x[4 * q + 1] = v.y;
        x[4 * q + 2] = v.z; x[4 * q + 3] = v.w;
    }

    // ---- 20x20 FMA; Mt/dvec uniform-CF -> s_load (scalar pipe) ----
    float lsum = 0.0f;
#pragma unroll
    for (int j = 0; j < D; ++j) {
        float t = dvec[j];
#pragma unroll
        for (int k = 0; k < D; ++k)
            t = fmaf(x[k], Mt[j * D + k], t);   // v_fma with SGPR src
        lsum += fmaxf(t, 0.0f);
    }
    lsum = valid ? lsum : 0.0f;  // mask clamped tail lanes

    // ---- Block reduction -> one partial per block ----
#pragma unroll
    for (int off = 32; off > 0; off >>= 1)
        lsum += __shfl_down(lsum, off, 64);
    if (lane == 0) wave_sums[wave] = lsum;
    __syncthreads();

    if (tid == 0) {
        const float bs = wave_sums[0] + wave_sums[1] + wave_sums[2] + wave_sums[3];
        // Release store + acq_rel ticket: visible to last block cross-XCD.
        __hip_atomic_store(&partials[bid], (double)bs, __ATOMIC_RELEASE,
                           __HIP_MEMORY_SCOPE_AGENT);
        const unsigned tk = __hip_atomic_fetch_add(counter, 1u, __ATOMIC_ACQ_REL,
                                                   __HIP_MEMORY_SCOPE_AGENT);
        is_last = (tk == gridDim.x - 1);
    }
    __syncthreads();

    // ---- Last block finalizes (no separate launch) ----
    if (is_last) {
        const int G = (int)gridDim.x;
        double a0 = 0.0, a1 = 0.0, a2 = 0.0, a3 = 0.0;  // 4-way ILP
        int i = tid;
        for (; i + 3 * BLOCK < G; i += 4 * BLOCK) {
            a0 += __hip_atomic_load(&partials[i], __ATOMIC_RELAXED,
                                    __HIP_MEMORY_SCOPE_AGENT);
            a1 += __hip_atomic_load(&partials[i + BLOCK], __ATOMIC_RELAXED,
                                    __HIP_MEMORY_SCOPE_AGENT);
            a2 += __hip_atomic_load(&partials[i + 2 * BLOCK], __ATOMIC_RELAXED,
                                    __HIP_MEMORY_SCOPE_AGENT);
            a3 += __hip_atomic_load(&partials[i + 3 * BLOCK], __ATOMIC_RELAXED,
                                    __HIP_MEMORY_SCOPE_AGENT);
        }
        for (; i < G; i += BLOCK)
            a0 += __hip_atomic_load(&partials[i], __ATOMIC_RELAXED,
                                    __HIP_MEMORY_SCOPE_AGENT);
        double sd = (a0 + a1) + (a2 + a3);
#pragma unroll
        for (int off = 32; off > 0; off >>= 1)
            sd += __shfl_down(sd, off, 64);
        if (lane == 0) dsum[wave] = sd;
        __syncthreads();
        if (tid == 0) {
            const double s0 = dsum[0] + dsum[1] + dsum[2] + dsum[3];
            float f = (float)s0;   // reference's s0 is f32
            while (f > 1.0f) f *= 0.5f;  // exact power-of-2 halvings
            out[0] = f;
        }
    }
}

extern "C" void kernel_launch(void* const* d_in, const int* in_sizes, int n_in,
                              void* d_out, int out_size, void* d_ws, size_t ws_size,
                              hipStream_t stream) {
    const float* X  = (const float*)d_in[0];
    const float* W  = (const float*)d_in[1];
    const float* b  = (const float*)d_in[2];
    const float* RW = (const float*)d_in[3];
    float* out = (float*)d_out;

    double* partials = (double*)d_ws;
    float*  Mt = (float*)((char*)d_ws + WS_PARTIALS_BYTES);
    float*  dv = Mt + D * D;
    unsigned* counter = (unsigned*)((char*)d_ws + WS_PARTIALS_BYTES + 1600 + 80);

    const int nrows = in_sizes[0] / (D * 4);  // 2,000,000

    setup_kernel<<<1, 256, 0, stream>>>(W, b, RW, Mt, dv, counter);

    const int blocks = (nrows + BLOCK - 1) / BLOCK;  // 7813
    fused_mlp_sum<<<blocks, BLOCK, 0, stream>>>(X, Mt, dv, partials, counter,
                                                out, nrows);
}